// Round 11
// baseline (275.422 us; speedup 1.0000x reference)
//
#include <hip/hip_runtime.h>
#include <hip/hip_fp16.h>

constexpr int TPB = 256;
constexpr int SH = 8;          // bucket = 256 consecutive destinations
constexpr int BD = 1 << SH;    // 256 dests per bucket (max 512 buckets -> n <= 131072)
constexpr int CHUNK = 4096;    // edges per binning block
constexpr int RMASK = (1 << 23) - 1;  // row in low 23 bits, local dest in high bits

typedef _Float16 half8 __attribute__((ext_vector_type(8)));
typedef float float4v __attribute__((ext_vector_type(4)));

__device__ __forceinline__ int wave_incl_scan(int x, int lane) {
#pragma unroll
  for (int d = 1; d < 64; d <<= 1) {
    int y = __shfl_up(x, d);
    if (lane >= d) x += y;
  }
  return x;
}

// ---------------- binned CSR build (grouped by destination) ----------------
// Edge entries are packed ints: (local_dest_in_bucket << 23) | src_row.
// Halves the staging traffic vs int2.

__global__ void bin_kernel(const int* __restrict__ row, const int* __restrict__ col,
                           int* __restrict__ bcur, int* __restrict__ binned,
                           int e, int nb, int cap) {
  __shared__ int h[512];
  __shared__ int base[512];
  for (int i = threadIdx.x; i < nb; i += TPB) h[i] = 0;
  __syncthreads();
  int cb = blockIdx.x * CHUNK;
  int lim = min(cb + CHUNK, e);
  for (int i = cb + threadIdx.x; i < lim; i += TPB)
    atomicAdd(&h[col[i] >> SH], 1);
  __syncthreads();
  for (int i = threadIdx.x; i < nb; i += TPB) {
    int c = h[i];
    base[i] = c ? (i * cap + atomicAdd(&bcur[i], c)) : 0;
    h[i] = 0;  // reuse as local cursor
  }
  __syncthreads();
  for (int i = cb + threadIdx.x; i < lim; i += TPB) {
    int c = col[i];  // L2-hot re-read of this block's own chunk
    int b = c >> SH;
    int p = base[b] + atomicAdd(&h[b], 1);
    binned[p] = ((c & (BD - 1)) << 23) | row[i];
  }
}

// per bucket: fine counts -> scan -> offs2/dinv -> place (fused; binned stays L2-hot)
// csr output stores the PLAIN row index (dest implicit in position).
__global__ __launch_bounds__(512) void count_place_kernel(
    const int* __restrict__ binned, const int* __restrict__ bcnt, int cap,
    int2* __restrict__ offs2, float* __restrict__ dinv, int* __restrict__ csr, int n) {
  __shared__ int cnt[BD];
  __shared__ int wsum[8];
  int t = threadIdx.x, lane = t & 63, wv = t >> 6;
  int b = blockIdx.x;
  int c0 = b << SH;
  int ndst = min(BD, n - c0);
  if (t < BD) cnt[t] = 0;
  __syncthreads();
  int beg = b * cap;
  int end = beg + bcnt[b];
  for (int i = beg + t; i < end; i += 512)
    atomicAdd(&cnt[(unsigned)binned[i] >> 23], 1);
  __syncthreads();
  int v = (t < BD) ? cnt[t] : 0;
  int ps = wave_incl_scan(v, lane);
  if (lane == 63) wsum[wv] = ps;
  __syncthreads();
  int woff = 0;
#pragma unroll
  for (int w = 0; w < 8; w++) woff += (w < wv) ? wsum[w] : 0;
  int ex = woff + ps - v;
  if (t < ndst) {
    offs2[c0 + t] = make_int2(beg + ex, beg + ex + v);
    dinv[c0 + t] = rsqrtf(1.0f + (float)v);  // deg = incoming + self-loop
  }
  __syncthreads();  // counts consumed; reuse cnt[] as cursors
  if (t < BD) cnt[t] = beg + ex;
  __syncthreads();
  for (int i = beg + t; i < end; i += 512) {
    int pv = binned[i];
    int p = atomicAdd(&cnt[(unsigned)pv >> 23], 1);
    csr[p] = pv & RMASK;  // plain row index for the agg kernels
  }
}

// ---------------- fused weight packing (+ bcur zero) ----------------

// Pack W[K,M] fp32 into B-fragment order for mfma_f32_16x16x32_f16:
// frag f = ct*KT+kt; lane holds B[k=kt*32+(lane>>4)*8+j][n=ct*16+(lane&15)].
template <int K, int M, int CT, int KT>
__device__ __forceinline__ void pack_one(const float* __restrict__ W,
                                         _Float16* __restrict__ P, int idx) {
  if (idx >= CT * KT * 64 * 8) return;
  int j = idx & 7;
  int lane = (idx >> 3) & 63;
  int f = idx >> 9;
  int kt = f % KT, ct = f / KT;
  int c = ct * 16 + (lane & 15);
  int k = kt * 32 + (lane >> 4) * 8 + j;
  float v = (c < M) ? W[k * M + c] : 0.f;
  P[idx] = (_Float16)v;
}

__global__ __launch_bounds__(256) void pack_all_kernel(
    const float* __restrict__ W1, const float* __restrict__ W2,
    const float* __restrict__ W3, _Float16* __restrict__ P1,
    _Float16* __restrict__ P2, _Float16* __restrict__ P3, int* __restrict__ bcur) {
  int blk = blockIdx.x, t = threadIdx.x;
  if (blk < 32) {
    pack_one<128, 64, 4, 4>(W1, P1, blk * 256 + t);
  } else if (blk < 48) {
    pack_one<64, 64, 4, 2>(W2, P2, (blk - 32) * 256 + t);
  } else if (blk < 60) {
    pack_one<64, 40, 3, 2>(W3, P3, (blk - 48) * 256 + t);
  } else {
    bcur[t] = 0;
    bcur[t + 256] = 0;
  }
}

// ---------------- layer-1 MFMA GEMM (fp32 in, fp16 out, dinv pre-scale) -----

template <int K, int M, int CT>
__global__ __launch_bounds__(256) void gemm_mfma_f32in(const float* __restrict__ x,
                                                       const _Float16* __restrict__ PW,
                                                       const float* __restrict__ dinv,
                                                       _Float16* __restrict__ out, int n) {
  constexpr int KT = K / 32;
  int lane = threadIdx.x & 63, wv = threadIdx.x >> 6;
  int m = lane & 15, q = lane >> 4;
  int row0w = blockIdx.x * 64 + wv * 16;
  int arow = row0w + m;
  int ar = arow < n ? arow : n - 1;  // clamp; stores are guarded
  const half8* pw = (const half8*)PW;

  float4v acc[CT];
#pragma unroll
  for (int ct = 0; ct < CT; ct++) acc[ct] = (float4v){0.f, 0.f, 0.f, 0.f};

#pragma unroll
  for (int kt = 0; kt < KT; kt++) {
    const float* xp = x + (size_t)ar * K + kt * 32 + q * 8;
    float4 x0 = *(const float4*)xp;
    float4 x1 = *(const float4*)(xp + 4);
    half8 a;
    a[0] = (_Float16)x0.x; a[1] = (_Float16)x0.y;
    a[2] = (_Float16)x0.z; a[3] = (_Float16)x0.w;
    a[4] = (_Float16)x1.x; a[5] = (_Float16)x1.y;
    a[6] = (_Float16)x1.z; a[7] = (_Float16)x1.w;
#pragma unroll
    for (int ct = 0; ct < CT; ct++) {
      half8 b = pw[(ct * KT + kt) * 64 + lane];
      acc[ct] = __builtin_amdgcn_mfma_f32_16x16x32_f16(a, b, acc[ct], 0, 0, 0);
    }
  }
  // D layout: col = lane&15, row = q*4 + reg
  int r0 = row0w + q * 4;
  float dv[4];
#pragma unroll
  for (int reg = 0; reg < 4; reg++) dv[reg] = (r0 + reg < n) ? dinv[r0 + reg] : 0.f;
#pragma unroll
  for (int ct = 0; ct < CT; ct++) {
    int c = ct * 16 + m;
    if (c < M) {
#pragma unroll
      for (int reg = 0; reg < 4; reg++) {
        int r = r0 + reg;
        if (r < n) out[(size_t)r * M + c] = (_Float16)(acc[ct][reg] * dv[reg]);
      }
    }
  }
}

// ---------------- half-slot aggregation core, BATCH-32 ----------------
// 16-lane slot owns one node. Lanes split into two halves (fl16>>3); half h
// accumulates edges 2j+h of each 32-edge batch: 16 predicated dwordx4
// gathers per lane in flight (256B/lane, 2x the batch-16 core). Two csr
// words per lane (rr0/rr1) cover the 32 indices; the shfl SOURCE VARIABLE is
// selected by compile-time j (j<8 -> rr0) — only the lane id depends on the
// runtime `half`. Next batch's csr loads issue under the gathers.
// NOTE: shfl broadcasts MUST be unconditional (round-2 bug: exec-masked
// source lane returns undefined data). Caller xor-8 merges the two halves.

__device__ __forceinline__ void h8_add(uint4 u, float* acc) {
  __half2 h0 = *(__half2*)&u.x, h1 = *(__half2*)&u.y;
  __half2 h2 = *(__half2*)&u.z, h3 = *(__half2*)&u.w;
  float2 f0 = __half22float2(h0), f1 = __half22float2(h1);
  float2 f2 = __half22float2(h2), f3 = __half22float2(h3);
  acc[0] += f0.x; acc[1] += f0.y; acc[2] += f1.x; acc[3] += f1.y;
  acc[4] += f2.x; acc[5] += f2.y; acc[6] += f3.x; acc[7] += f3.y;
}

__device__ __forceinline__ uint4 pack_h8(const float* o) {
  __half2 h0 = __float22half2_rn(make_float2(o[0], o[1]));
  __half2 h1 = __float22half2_rn(make_float2(o[2], o[3]));
  __half2 h2 = __float22half2_rn(make_float2(o[4], o[5]));
  __half2 h3 = __float22half2_rn(make_float2(o[6], o[7]));
  uint4 u;
  u.x = *(unsigned*)&h0;
  u.y = *(unsigned*)&h1;
  u.z = *(unsigned*)&h2;
  u.w = *(unsigned*)&h3;
  return u;
}

__device__ __forceinline__ void agg_node(const uint4* __restrict__ xw4,
                                         const int* __restrict__ csr,
                                         int beg, int end, int sb, int half,
                                         int fl, int fl16, float* acc) {
  int b = beg;
  int rr0 = (b + fl16 < end) ? csr[b + fl16] : 0;
  int rr1 = (b + 16 + fl16 < end) ? csr[b + 16 + fl16] : 0;
  while (b < end) {
    int bn = b + 32;
    int cnt = end - b;  // slot-uniform
    // broadcast all 32 indices (unconditional shfl; var chosen by static j)
    int r[16];
#pragma unroll
    for (int j = 0; j < 16; j++) {
      int ej = 2 * j + half;                       // 0..31
      r[j] = __shfl(j < 8 ? rr0 : rr1, sb + (ej & 15));
    }
    // issue up to 16 independent gathers per lane
    uint4 u[16];
#pragma unroll
    for (int j = 0; j < 16; j++) {
      int ej = 2 * j + half;
      if (ej < cnt) u[j] = xw4[(size_t)r[j] * 8 + fl];
    }
    // prefetch next batch's csr under the gathers
    rr0 = (bn + fl16 < end) ? csr[bn + fl16] : 0;
    rr1 = (bn + 16 + fl16 < end) ? csr[bn + 16 + fl16] : 0;
    // accumulate
#pragma unroll
    for (int j = 0; j < 16; j++) {
      int ej = 2 * j + half;
      if (ej < cnt) h8_add(u[j], acc);
    }
    b = bn;
  }
}

// ---------------- standalone mid aggregation (layer-2) ----------------
// out = relu(acc*di + b2) * di   (pre-scaled for the layer-3 pre-agg)

__global__ __launch_bounds__(256) void agg_mid_kernel(
    const uint4* __restrict__ xw4, const float* __restrict__ dinv,
    const int* __restrict__ csr, const int2* __restrict__ offs2,
    const float* __restrict__ bias, uint4* __restrict__ out4, int n) {
  int lane = threadIdx.x & 63, wv = threadIdx.x >> 6;
  int sl = lane >> 4, fl16 = lane & 15, half = fl16 >> 3, fl = fl16 & 7;
  int sb = sl << 4;
  int i = blockIdx.x * 16 + wv * 4 + sl;
  bool valid = i < n;
  int ic = valid ? i : n - 1;
  int2 oe = offs2[ic];
  int beg = oe.x;
  int end = valid ? oe.y : beg;
  float di = dinv[ic];
  float acc[8] = {0.f, 0.f, 0.f, 0.f, 0.f, 0.f, 0.f, 0.f};
  if (!half) h8_add(xw4[(size_t)ic * 8 + fl], acc);  // self-loop (pre-scaled row)
  agg_node(xw4, csr, beg, end, sb, half, fl, fl16, acc);
#pragma unroll
  for (int k = 0; k < 8; k++) acc[k] += __shfl_xor(acc[k], 8);

  if (valid && !half) {
    const float4* b4 = (const float4*)bias;
    float4 ba = b4[fl * 2], bb = b4[fl * 2 + 1];
    float o[8];
    o[0] = fmaxf(acc[0] * di + ba.x, 0.f) * di;
    o[1] = fmaxf(acc[1] * di + ba.y, 0.f) * di;
    o[2] = fmaxf(acc[2] * di + ba.z, 0.f) * di;
    o[3] = fmaxf(acc[3] * di + ba.w, 0.f) * di;
    o[4] = fmaxf(acc[4] * di + bb.x, 0.f) * di;
    o[5] = fmaxf(acc[5] * di + bb.y, 0.f) * di;
    o[6] = fmaxf(acc[6] * di + bb.z, 0.f) * di;
    o[7] = fmaxf(acc[7] * di + bb.w, 0.f) * di;
    out4[(size_t)i * 8 + fl] = pack_h8(o);
  }
}

// ---------------- fused aggregation + MFMA GEMM ----------------
// Block owns 64 destination rows: 16 slots x 4 sequential nodes aggregate into
// an LDS fp16 tile (stride 72 halves = 144B), then 4 waves run the K=64 MFMA
// GEMM straight from LDS. NOTE: no cross-node prefetch arrays — runtime-
// indexed register arrays in the un-unrolled node loop go to scratch
// (round-9 regression, −20 µs/kernel).
// FMODE 0 (layers 1->2): agg epilogue relu(acc*di + biasA); gemm out fp16 *dinv[r].
// FMODE 1 (layer 3):     agg epilogue acc*di;               gemm out fp32 + biasG.

template <int M, int CT, int FMODE>
__global__ __launch_bounds__(256) void fused_agg_gemm(
    const uint4* __restrict__ xw4, const float* __restrict__ dinv,
    const int* __restrict__ csr, const int2* __restrict__ offs2,
    const float* __restrict__ biasA, const float* __restrict__ biasG,
    const _Float16* __restrict__ PW, void* __restrict__ outp, int n) {
  constexpr int KT = 2;  // K = 64
  __shared__ _Float16 tile[64 * 72];
  int lane = threadIdx.x & 63, wv = threadIdx.x >> 6;
  int sl = lane >> 4, fl16 = lane & 15, half = fl16 >> 3, fl = fl16 & 7;
  int sb = sl << 4;
  int slot_id = wv * 4 + sl;  // 0..15
  int base = blockIdx.x * 64;

#pragma unroll 1
  for (int nd = 0; nd < 4; nd++) {
    int l = slot_id * 4 + nd;  // local row 0..63
    int i = base + l;
    bool valid = i < n;
    int ic = valid ? i : n - 1;
    int2 oe = offs2[ic];
    int beg = oe.x;
    int end = valid ? oe.y : beg;
    float di = dinv[ic];
    float acc[8] = {0.f, 0.f, 0.f, 0.f, 0.f, 0.f, 0.f, 0.f};
    if (!half) h8_add(xw4[(size_t)ic * 8 + fl], acc);  // self-loop
    agg_node(xw4, csr, beg, end, sb, half, fl, fl16, acc);
#pragma unroll
    for (int k = 0; k < 8; k++) acc[k] += __shfl_xor(acc[k], 8);

    float o[8];
    if (FMODE == 0) {
      const float4* b4 = (const float4*)biasA;
      float4 ba = b4[fl * 2], bb = b4[fl * 2 + 1];
      o[0] = fmaxf(acc[0] * di + ba.x, 0.f);
      o[1] = fmaxf(acc[1] * di + ba.y, 0.f);
      o[2] = fmaxf(acc[2] * di + ba.z, 0.f);
      o[3] = fmaxf(acc[3] * di + ba.w, 0.f);
      o[4] = fmaxf(acc[4] * di + bb.x, 0.f);
      o[5] = fmaxf(acc[5] * di + bb.y, 0.f);
      o[6] = fmaxf(acc[6] * di + bb.z, 0.f);
      o[7] = fmaxf(acc[7] * di + bb.w, 0.f);
    } else {
#pragma unroll
      for (int k = 0; k < 8; k++) o[k] = acc[k] * di;
    }
    if (!half) *(uint4*)&tile[(size_t)l * 72 + fl * 8] = pack_h8(o);
  }
  __syncthreads();

  // ---- MFMA phase (same fragment mapping as the standalone GEMMs) ----
  int m = lane & 15, q = lane >> 4;
  int lrow = wv * 16 + m;
  const half8* pw = (const half8*)PW;
  float4v accd[CT];
#pragma unroll
  for (int ct = 0; ct < CT; ct++) accd[ct] = (float4v){0.f, 0.f, 0.f, 0.f};
#pragma unroll
  for (int kt = 0; kt < KT; kt++) {
    half8 a = *(const half8*)&tile[lrow * 72 + kt * 32 + q * 8];
#pragma unroll
    for (int ct = 0; ct < CT; ct++) {
      half8 b = pw[(ct * KT + kt) * 64 + lane];
      accd[ct] = __builtin_amdgcn_mfma_f32_16x16x32_f16(a, b, accd[ct], 0, 0, 0);
    }
  }
  int r0 = base + wv * 16 + q * 4;
  if (FMODE == 0) {
    _Float16* out = (_Float16*)outp;
    float dv[4];
#pragma unroll
    for (int reg = 0; reg < 4; reg++) dv[reg] = (r0 + reg < n) ? dinv[r0 + reg] : 0.f;
#pragma unroll
    for (int ct = 0; ct < CT; ct++) {
      int c = ct * 16 + m;
      if (c < M) {
#pragma unroll
        for (int reg = 0; reg < 4; reg++) {
          int r = r0 + reg;
          if (r < n) out[(size_t)r * M + c] = (_Float16)(accd[ct][reg] * dv[reg]);
        }
      }
    }
  } else {
    float* out = (float*)outp;
#pragma unroll
    for (int ct = 0; ct < CT; ct++) {
      int c = ct * 16 + m;
      if (c < M) {
        float bb = biasG[c];
#pragma unroll
        for (int reg = 0; reg < 4; reg++) {
          int r = r0 + reg;
          if (r < n) out[(size_t)r * M + c] = accd[ct][reg] + bb;
        }
      }
    }
  }
}

// ---------------- launcher ----------------

extern "C" void kernel_launch(void* const* d_in, const int* in_sizes, int n_in,
                              void* d_out, int out_size, void* d_ws, size_t ws_size,
                              hipStream_t stream) {
  const float* x  = (const float*)d_in[0];
  const int*   ei = (const int*)d_in[1];
  const float* W1 = (const float*)d_in[2];
  const float* b1 = (const float*)d_in[3];
  const float* W2 = (const float*)d_in[4];
  const float* b2 = (const float*)d_in[5];
  const float* W3 = (const float*)d_in[6];
  const float* b3 = (const float*)d_in[7];

  int n = in_sizes[0] / 128;
  int e = in_sizes[1] / 2;
  const int* rowA = ei;      // edge_index[0] = source
  const int* colA = ei + e;  // edge_index[1] = destination (segment id)

  int nb = (n + BD - 1) >> SH;  // buckets (<= 512)
  int meanb = e / nb;
  int cap = meanb + (meanb / 4 > 1024 ? meanb / 4 : 1024);  // generous slack
  int nch = (e + CHUNK - 1) / CHUNK;

  size_t off = 0;
  auto alloc = [&](size_t bytes) {
    void* p = (char*)d_ws + off;
    off += (bytes + 255) & ~(size_t)255;
    return p;
  };
  // bufA (n*64*4 B) also aliases the binned edge array (nb*cap*4 << n*256 B)
  __half* bufA  = (__half*)alloc((size_t)n * 64 * 4);
  __half* bufB  = (__half*)alloc((size_t)n * 64 * 4);
  int2*  offs2  = (int2*)alloc((size_t)n * 8);
  float* dinv   = (float*)alloc((size_t)n * 4);
  int*   csr    = (int*)alloc((size_t)nb * cap * 4);
  int*   bcur   = (int*)alloc(512 * 4);
  _Float16* PW1 = (_Float16*)alloc(4 * 4 * 64 * 8 * 2);  // CT=4, KT=4
  _Float16* PW2 = (_Float16*)alloc(4 * 2 * 64 * 8 * 2);  // CT=4, KT=2
  _Float16* PW3 = (_Float16*)alloc(3 * 2 * 64 * 8 * 2);  // CT=3, KT=2
  int*   binned = (int*)bufA;  // consumed by count_place before gemm1 writes bufA
  (void)ws_size; (void)n_in; (void)out_size;

  // fused: pack all three W matrices + zero bcur (one dispatch)
  pack_all_kernel<<<61, TPB, 0, stream>>>(W1, W2, W3, PW1, PW2, PW3, bcur);
  bin_kernel<<<nch, TPB, 0, stream>>>(rowA, colA, bcur, binned, e, nb, cap);
  count_place_kernel<<<nb, 512, 0, stream>>>(binned, bcur, cap, offs2, dinv, csr, n);

  int gmf = (n + 63) / 64;   // 64 rows/block
  int gagg = (n + 15) / 16;  // 16 nodes/block (4 slots/wave x 4 waves)

  // L1 GEMM: bufA = (x @ W1) * dinv[row]
  gemm_mfma_f32in<128, 64, 4><<<gmf, TPB, 0, stream>>>(x, PW1, dinv, (_Float16*)bufA, n);
  // agg0 + gemm2 fused: bufB = (relu(L(bufA) + b1) @ W2) * dinv[row]
  fused_agg_gemm<64, 4, 0><<<gmf, TPB, 0, stream>>>(
      (const uint4*)bufA, dinv, csr, offs2, b1, nullptr, PW2, bufB, n);
  // agg1: bufA = relu(L(bufB) + b2) * dinv[row]
  agg_mid_kernel<<<gagg, TPB, 0, stream>>>((const uint4*)bufB, dinv, csr, offs2,
                                           b2, (uint4*)bufA, n);
  // agg2 + gemm3 fused: out = L(bufA) @ W3 + b3  (fp32)
  fused_agg_gemm<40, 3, 1><<<gmf, TPB, 0, stream>>>(
      (const uint4*)bufA, dinv, csr, offs2, nullptr, b3, PW3, d_out, n);
}

// Round 12
// 256.597 us; speedup vs baseline: 1.0734x; 1.0734x over previous
//
#include <hip/hip_runtime.h>
#include <hip/hip_fp16.h>

constexpr int TPB = 256;
constexpr int SH = 8;          // bucket = 256 consecutive destinations
constexpr int BD = 1 << SH;    // 256 dests per bucket (max 512 buckets -> n <= 131072)
constexpr int CHUNK = 4096;    // edges per binning block
constexpr int RMASK = (1 << 23) - 1;  // row in low 23 bits, local dest in high bits

typedef _Float16 half8 __attribute__((ext_vector_type(8)));
typedef float float4v __attribute__((ext_vector_type(4)));

__device__ __forceinline__ int wave_incl_scan(int x, int lane) {
#pragma unroll
  for (int d = 1; d < 64; d <<= 1) {
    int y = __shfl_up(x, d);
    if (lane >= d) x += y;
  }
  return x;
}

// ---------------- binned CSR build (grouped by destination) ----------------
// Edge entries are packed ints: (local_dest_in_bucket << 23) | src_row.

__global__ void bin_kernel(const int* __restrict__ row, const int* __restrict__ col,
                           int* __restrict__ bcur, int* __restrict__ binned,
                           int e, int nb, int cap) {
  __shared__ int h[512];
  __shared__ int base[512];
  for (int i = threadIdx.x; i < nb; i += TPB) h[i] = 0;
  __syncthreads();
  int cb = blockIdx.x * CHUNK;
  int lim = min(cb + CHUNK, e);
  for (int i = cb + threadIdx.x; i < lim; i += TPB)
    atomicAdd(&h[col[i] >> SH], 1);
  __syncthreads();
  for (int i = threadIdx.x; i < nb; i += TPB) {
    int c = h[i];
    base[i] = c ? (i * cap + atomicAdd(&bcur[i], c)) : 0;
    h[i] = 0;  // reuse as local cursor
  }
  __syncthreads();
  for (int i = cb + threadIdx.x; i < lim; i += TPB) {
    int c = col[i];  // L2-hot re-read of this block's own chunk
    int b = c >> SH;
    int p = base[b] + atomicAdd(&h[b], 1);
    binned[p] = ((c & (BD - 1)) << 23) | row[i];
  }
}

// per bucket: fine counts -> scan -> offs2/dinv -> place (fused; binned stays L2-hot)
// csr output stores the PLAIN row index (dest implicit in position).
__global__ __launch_bounds__(512) void count_place_kernel(
    const int* __restrict__ binned, const int* __restrict__ bcnt, int cap,
    int2* __restrict__ offs2, float* __restrict__ dinv, int* __restrict__ csr, int n) {
  __shared__ int cnt[BD];
  __shared__ int wsum[8];
  int t = threadIdx.x, lane = t & 63, wv = t >> 6;
  int b = blockIdx.x;
  int c0 = b << SH;
  int ndst = min(BD, n - c0);
  if (t < BD) cnt[t] = 0;
  __syncthreads();
  int beg = b * cap;
  int end = beg + bcnt[b];
  for (int i = beg + t; i < end; i += 512)
    atomicAdd(&cnt[(unsigned)binned[i] >> 23], 1);
  __syncthreads();
  int v = (t < BD) ? cnt[t] : 0;
  int ps = wave_incl_scan(v, lane);
  if (lane == 63) wsum[wv] = ps;
  __syncthreads();
  int woff = 0;
#pragma unroll
  for (int w = 0; w < 8; w++) woff += (w < wv) ? wsum[w] : 0;
  int ex = woff + ps - v;
  if (t < ndst) {
    offs2[c0 + t] = make_int2(beg + ex, beg + ex + v);
    dinv[c0 + t] = rsqrtf(1.0f + (float)v);  // deg = incoming + self-loop
  }
  __syncthreads();  // counts consumed; reuse cnt[] as cursors
  if (t < BD) cnt[t] = beg + ex;
  __syncthreads();
  for (int i = beg + t; i < end; i += 512) {
    int pv = binned[i];
    int p = atomicAdd(&cnt[(unsigned)pv >> 23], 1);
    csr[p] = pv & RMASK;  // plain row index for the agg kernels
  }
}

// ---------------- fused weight packing (+ bcur zero) ----------------

// Pack W[K,M] fp32 into B-fragment order for mfma_f32_16x16x32_f16:
// frag f = ct*KT+kt; lane holds B[k=kt*32+(lane>>4)*8+j][n=ct*16+(lane&15)].
template <int K, int M, int CT, int KT>
__device__ __forceinline__ void pack_one(const float* __restrict__ W,
                                         _Float16* __restrict__ P, int idx) {
  if (idx >= CT * KT * 64 * 8) return;
  int j = idx & 7;
  int lane = (idx >> 3) & 63;
  int f = idx >> 9;
  int kt = f % KT, ct = f / KT;
  int c = ct * 16 + (lane & 15);
  int k = kt * 32 + (lane >> 4) * 8 + j;
  float v = (c < M) ? W[k * M + c] : 0.f;
  P[idx] = (_Float16)v;
}

__global__ __launch_bounds__(256) void pack_all_kernel(
    const float* __restrict__ W1, const float* __restrict__ W2,
    const float* __restrict__ W3, _Float16* __restrict__ P1,
    _Float16* __restrict__ P2, _Float16* __restrict__ P3, int* __restrict__ bcur) {
  int blk = blockIdx.x, t = threadIdx.x;
  if (blk < 32) {
    pack_one<128, 64, 4, 4>(W1, P1, blk * 256 + t);
  } else if (blk < 48) {
    pack_one<64, 64, 4, 2>(W2, P2, (blk - 32) * 256 + t);
  } else if (blk < 60) {
    pack_one<64, 40, 3, 2>(W3, P3, (blk - 48) * 256 + t);
  } else {
    bcur[t] = 0;
    bcur[t + 256] = 0;
  }
}

// ---------------- layer-1 MFMA GEMM (fp32 in, fp16 out, dinv pre-scale) -----

template <int K, int M, int CT>
__global__ __launch_bounds__(256) void gemm_mfma_f32in(const float* __restrict__ x,
                                                       const _Float16* __restrict__ PW,
                                                       const float* __restrict__ dinv,
                                                       _Float16* __restrict__ out, int n) {
  constexpr int KT = K / 32;
  int lane = threadIdx.x & 63, wv = threadIdx.x >> 6;
  int m = lane & 15, q = lane >> 4;
  int row0w = blockIdx.x * 64 + wv * 16;
  int arow = row0w + m;
  int ar = arow < n ? arow : n - 1;  // clamp; stores are guarded
  const half8* pw = (const half8*)PW;

  float4v acc[CT];
#pragma unroll
  for (int ct = 0; ct < CT; ct++) acc[ct] = (float4v){0.f, 0.f, 0.f, 0.f};

#pragma unroll
  for (int kt = 0; kt < KT; kt++) {
    const float* xp = x + (size_t)ar * K + kt * 32 + q * 8;
    float4 x0 = *(const float4*)xp;
    float4 x1 = *(const float4*)(xp + 4);
    half8 a;
    a[0] = (_Float16)x0.x; a[1] = (_Float16)x0.y;
    a[2] = (_Float16)x0.z; a[3] = (_Float16)x0.w;
    a[4] = (_Float16)x1.x; a[5] = (_Float16)x1.y;
    a[6] = (_Float16)x1.z; a[7] = (_Float16)x1.w;
#pragma unroll
    for (int ct = 0; ct < CT; ct++) {
      half8 b = pw[(ct * KT + kt) * 64 + lane];
      acc[ct] = __builtin_amdgcn_mfma_f32_16x16x32_f16(a, b, acc[ct], 0, 0, 0);
    }
  }
  // D layout: col = lane&15, row = q*4 + reg
  int r0 = row0w + q * 4;
  float dv[4];
#pragma unroll
  for (int reg = 0; reg < 4; reg++) dv[reg] = (r0 + reg < n) ? dinv[r0 + reg] : 0.f;
#pragma unroll
  for (int ct = 0; ct < CT; ct++) {
    int c = ct * 16 + m;
    if (c < M) {
#pragma unroll
      for (int reg = 0; reg < 4; reg++) {
        int r = r0 + reg;
        if (r < n) out[(size_t)r * M + c] = (_Float16)(acc[ct][reg] * dv[reg]);
      }
    }
  }
}

// ---------------- half-slot aggregation core, BATCH-16 (R10 optimum) --------
// 16-lane slot owns one node. Lanes split into two halves (fl16>>3); half h
// accumulates edges 2j+h of each 16-edge batch, so one dwordx4 gather
// instruction fetches 2 full 128B rows per slot. csr batch for the NEXT
// iteration is prefetched before the current gathers (latency overlap).
// Batch-16 is the measured MLP x occupancy optimum: batch-8 = 2.0 TB/s,
// batch-16 = 2.5 TB/s, batch-32 = 1.84 TB/s (VGPR 88 -> occupancy 16%).
// NOTE: the __shfl broadcast MUST be unconditional — the ej<cnt predicate is
// non-uniform across the two halves; a shfl from an exec-masked-out source
// lane returns undefined data (round-2 bug).
// Caller must xor-8 merge the two halves' partial sums.

__device__ __forceinline__ void h8_add(uint4 u, float* acc) {
  __half2 h0 = *(__half2*)&u.x, h1 = *(__half2*)&u.y;
  __half2 h2 = *(__half2*)&u.z, h3 = *(__half2*)&u.w;
  float2 f0 = __half22float2(h0), f1 = __half22float2(h1);
  float2 f2 = __half22float2(h2), f3 = __half22float2(h3);
  acc[0] += f0.x; acc[1] += f0.y; acc[2] += f1.x; acc[3] += f1.y;
  acc[4] += f2.x; acc[5] += f2.y; acc[6] += f3.x; acc[7] += f3.y;
}

__device__ __forceinline__ uint4 pack_h8(const float* o) {
  __half2 h0 = __float22half2_rn(make_float2(o[0], o[1]));
  __half2 h1 = __float22half2_rn(make_float2(o[2], o[3]));
  __half2 h2 = __float22half2_rn(make_float2(o[4], o[5]));
  __half2 h3 = __float22half2_rn(make_float2(o[6], o[7]));
  uint4 u;
  u.x = *(unsigned*)&h0;
  u.y = *(unsigned*)&h1;
  u.z = *(unsigned*)&h2;
  u.w = *(unsigned*)&h3;
  return u;
}

__device__ __forceinline__ void agg_node(const uint4* __restrict__ xw4,
                                         const int* __restrict__ csr,
                                         int beg, int end, int sb, int half,
                                         int fl, int fl16, float* acc) {
  int b = beg;
  int idx0 = b + fl16;
  int rr = (idx0 < end) ? csr[idx0] : 0;
  while (b < end) {
    int bn = b + 16;
    int idxn = bn + fl16;
    int rn = (idxn < end) ? csr[idxn] : 0;  // prefetch next batch under gathers
    int cnt = end - b;                      // slot-uniform
    uint4 u[8];
    int r[8];
#pragma unroll
    for (int j = 0; j < 8; j++) {
      int ej = 2 * j + half;
      r[j] = __shfl(rr, sb + ej);  // unconditional: all slot lanes active
    }
#pragma unroll
    for (int j = 0; j < 8; j++) {
      int ej = 2 * j + half;
      if (ej < cnt) u[j] = xw4[(size_t)r[j] * 8 + fl];
    }
#pragma unroll
    for (int j = 0; j < 8; j++) {
      int ej = 2 * j + half;
      if (ej < cnt) h8_add(u[j], acc);
    }
    rr = rn;
    b = bn;
  }
}

// ---------------- standalone mid aggregation (layer-2) ----------------
// out = relu(acc*di + b2) * di   (pre-scaled for the layer-3 pre-agg)

__global__ __launch_bounds__(256) void agg_mid_kernel(
    const uint4* __restrict__ xw4, const float* __restrict__ dinv,
    const int* __restrict__ csr, const int2* __restrict__ offs2,
    const float* __restrict__ bias, uint4* __restrict__ out4, int n) {
  int lane = threadIdx.x & 63, wv = threadIdx.x >> 6;
  int sl = lane >> 4, fl16 = lane & 15, half = fl16 >> 3, fl = fl16 & 7;
  int sb = sl << 4;
  int i = blockIdx.x * 16 + wv * 4 + sl;
  bool valid = i < n;
  int ic = valid ? i : n - 1;
  int2 oe = offs2[ic];
  int beg = oe.x;
  int end = valid ? oe.y : beg;
  float di = dinv[ic];
  float acc[8] = {0.f, 0.f, 0.f, 0.f, 0.f, 0.f, 0.f, 0.f};
  if (!half) h8_add(xw4[(size_t)ic * 8 + fl], acc);  // self-loop (pre-scaled row)
  agg_node(xw4, csr, beg, end, sb, half, fl, fl16, acc);
#pragma unroll
  for (int k = 0; k < 8; k++) acc[k] += __shfl_xor(acc[k], 8);

  if (valid && !half) {
    const float4* b4 = (const float4*)bias;
    float4 ba = b4[fl * 2], bb = b4[fl * 2 + 1];
    float o[8];
    o[0] = fmaxf(acc[0] * di + ba.x, 0.f) * di;
    o[1] = fmaxf(acc[1] * di + ba.y, 0.f) * di;
    o[2] = fmaxf(acc[2] * di + ba.z, 0.f) * di;
    o[3] = fmaxf(acc[3] * di + ba.w, 0.f) * di;
    o[4] = fmaxf(acc[4] * di + bb.x, 0.f) * di;
    o[5] = fmaxf(acc[5] * di + bb.y, 0.f) * di;
    o[6] = fmaxf(acc[6] * di + bb.z, 0.f) * di;
    o[7] = fmaxf(acc[7] * di + bb.w, 0.f) * di;
    out4[(size_t)i * 8 + fl] = pack_h8(o);
  }
}

// ---------------- fused aggregation + MFMA GEMM (32 dests/block) ------------
// Block owns 32 destination rows: 16 slots x 2 sequential nodes (half the
// serial chain and tail imbalance of the 64-dest version; grid 2x deeper).
// Agg into an LDS fp16 tile (stride 72 halves), then 4 waves run the K=64
// MFMA GEMM: wave wv covers row-group (wv&1)*16 and ct-half (wv>>1).
// NOTE: no cross-node prefetch arrays — runtime-indexed register arrays in
// the un-unrolled node loop go to scratch (round-9 regression).
// FMODE 0 (layers 1->2): agg epilogue relu(acc*di + biasA); gemm out fp16 *dinv[r].
// FMODE 1 (layer 3):     agg epilogue acc*di;               gemm out fp32 + biasG.

template <int M, int CT, int FMODE>
__global__ __launch_bounds__(256) void fused_agg_gemm(
    const uint4* __restrict__ xw4, const float* __restrict__ dinv,
    const int* __restrict__ csr, const int2* __restrict__ offs2,
    const float* __restrict__ biasA, const float* __restrict__ biasG,
    const _Float16* __restrict__ PW, void* __restrict__ outp, int n) {
  constexpr int KT = 2;  // K = 64
  __shared__ _Float16 tile[32 * 72];
  int lane = threadIdx.x & 63, wv = threadIdx.x >> 6;
  int sl = lane >> 4, fl16 = lane & 15, half = fl16 >> 3, fl = fl16 & 7;
  int sb = sl << 4;
  int slot_id = wv * 4 + sl;  // 0..15
  int base = blockIdx.x * 32;

#pragma unroll 1
  for (int nd = 0; nd < 2; nd++) {
    int l = slot_id * 2 + nd;  // local row 0..31
    int i = base + l;
    bool valid = i < n;
    int ic = valid ? i : n - 1;
    int2 oe = offs2[ic];
    int beg = oe.x;
    int end = valid ? oe.y : beg;
    float di = dinv[ic];
    float acc[8] = {0.f, 0.f, 0.f, 0.f, 0.f, 0.f, 0.f, 0.f};
    if (!half) h8_add(xw4[(size_t)ic * 8 + fl], acc);  // self-loop
    agg_node(xw4, csr, beg, end, sb, half, fl, fl16, acc);
#pragma unroll
    for (int k = 0; k < 8; k++) acc[k] += __shfl_xor(acc[k], 8);

    float o[8];
    if (FMODE == 0) {
      const float4* b4 = (const float4*)biasA;
      float4 ba = b4[fl * 2], bb = b4[fl * 2 + 1];
      o[0] = fmaxf(acc[0] * di + ba.x, 0.f);
      o[1] = fmaxf(acc[1] * di + ba.y, 0.f);
      o[2] = fmaxf(acc[2] * di + ba.z, 0.f);
      o[3] = fmaxf(acc[3] * di + ba.w, 0.f);
      o[4] = fmaxf(acc[4] * di + bb.x, 0.f);
      o[5] = fmaxf(acc[5] * di + bb.y, 0.f);
      o[6] = fmaxf(acc[6] * di + bb.z, 0.f);
      o[7] = fmaxf(acc[7] * di + bb.w, 0.f);
    } else {
#pragma unroll
      for (int k = 0; k < 8; k++) o[k] = acc[k] * di;
    }
    if (!half) *(uint4*)&tile[(size_t)l * 72 + fl * 8] = pack_h8(o);
  }
  __syncthreads();

  // ---- MFMA phase: wave wv -> rows (wv&1)*16..+16, ct-half (wv>>1) ----
  int m = lane & 15, q = lane >> 4;
  int rg = wv & 1, ch = wv >> 1;
  int lrow = rg * 16 + m;
  const half8* pw = (const half8*)PW;
  float4v accd[2];
#pragma unroll
  for (int c2 = 0; c2 < 2; c2++) accd[c2] = (float4v){0.f, 0.f, 0.f, 0.f};
#pragma unroll
  for (int kt = 0; kt < KT; kt++) {
    half8 a = *(const half8*)&tile[lrow * 72 + kt * 32 + q * 8];
#pragma unroll
    for (int c2 = 0; c2 < 2; c2++) {
      int ct = ch * 2 + c2;
      if (ct < CT) {
        half8 b = pw[(ct * KT + kt) * 64 + lane];
        accd[c2] = __builtin_amdgcn_mfma_f32_16x16x32_f16(a, b, accd[c2], 0, 0, 0);
      }
    }
  }
  int r0 = base + rg * 16 + q * 4;
  if (FMODE == 0) {
    _Float16* out = (_Float16*)outp;
    float dv[4];
#pragma unroll
    for (int reg = 0; reg < 4; reg++) dv[reg] = (r0 + reg < n) ? dinv[r0 + reg] : 0.f;
#pragma unroll
    for (int c2 = 0; c2 < 2; c2++) {
      int ct = ch * 2 + c2;
      int c = ct * 16 + m;
      if (ct < CT && c < M) {
#pragma unroll
        for (int reg = 0; reg < 4; reg++) {
          int r = r0 + reg;
          if (r < n) out[(size_t)r * M + c] = (_Float16)(accd[c2][reg] * dv[reg]);
        }
      }
    }
  } else {
    float* out = (float*)outp;
#pragma unroll
    for (int c2 = 0; c2 < 2; c2++) {
      int ct = ch * 2 + c2;
      int c = ct * 16 + m;
      if (ct < CT && c < M) {
        float bb = biasG[c];
#pragma unroll
        for (int reg = 0; reg < 4; reg++) {
          int r = r0 + reg;
          if (r < n) out[(size_t)r * M + c] = accd[c2][reg] + bb;
        }
      }
    }
  }
}

// ---------------- launcher ----------------

extern "C" void kernel_launch(void* const* d_in, const int* in_sizes, int n_in,
                              void* d_out, int out_size, void* d_ws, size_t ws_size,
                              hipStream_t stream) {
  const float* x  = (const float*)d_in[0];
  const int*   ei = (const int*)d_in[1];
  const float* W1 = (const float*)d_in[2];
  const float* b1 = (const float*)d_in[3];
  const float* W2 = (const float*)d_in[4];
  const float* b2 = (const float*)d_in[5];
  const float* W3 = (const float*)d_in[6];
  const float* b3 = (const float*)d_in[7];

  int n = in_sizes[0] / 128;
  int e = in_sizes[1] / 2;
  const int* rowA = ei;      // edge_index[0] = source
  const int* colA = ei + e;  // edge_index[1] = destination (segment id)

  int nb = (n + BD - 1) >> SH;  // buckets (<= 512)
  int meanb = e / nb;
  int cap = meanb + (meanb / 4 > 1024 ? meanb / 4 : 1024);  // generous slack
  int nch = (e + CHUNK - 1) / CHUNK;

  size_t off = 0;
  auto alloc = [&](size_t bytes) {
    void* p = (char*)d_ws + off;
    off += (bytes + 255) & ~(size_t)255;
    return p;
  };
  // bufA (n*64*4 B) also aliases the binned edge array (nb*cap*4 << n*256 B)
  __half* bufA  = (__half*)alloc((size_t)n * 64 * 4);
  __half* bufB  = (__half*)alloc((size_t)n * 64 * 4);
  int2*  offs2  = (int2*)alloc((size_t)n * 8);
  float* dinv   = (float*)alloc((size_t)n * 4);
  int*   csr    = (int*)alloc((size_t)nb * cap * 4);
  int*   bcur   = (int*)alloc(512 * 4);
  _Float16* PW1 = (_Float16*)alloc(4 * 4 * 64 * 8 * 2);  // CT=4, KT=4
  _Float16* PW2 = (_Float16*)alloc(4 * 2 * 64 * 8 * 2);  // CT=4, KT=2
  _Float16* PW3 = (_Float16*)alloc(3 * 2 * 64 * 8 * 2);  // CT=3, KT=2
  int*   binned = (int*)bufA;  // consumed by count_place before gemm1 writes bufA
  (void)ws_size; (void)n_in; (void)out_size;

  // fused: pack all three W matrices + zero bcur (one dispatch)
  pack_all_kernel<<<61, TPB, 0, stream>>>(W1, W2, W3, PW1, PW2, PW3, bcur);
  bin_kernel<<<nch, TPB, 0, stream>>>(rowA, colA, bcur, binned, e, nb, cap);
  count_place_kernel<<<nb, 512, 0, stream>>>(binned, bcur, cap, offs2, dinv, csr, n);

  int gmf = (n + 63) / 64;   // layer-1 GEMM: 64 rows/block
  int gfa = (n + 31) / 32;   // fused agg+gemm: 32 dests/block
  int gagg = (n + 15) / 16;  // mid agg: 16 nodes/block (4 slots/wave x 4 waves)

  // L1 GEMM: bufA = (x @ W1) * dinv[row]
  gemm_mfma_f32in<128, 64, 4><<<gmf, TPB, 0, stream>>>(x, PW1, dinv, (_Float16*)bufA, n);
  // agg0 + gemm2 fused: bufB = (relu(L(bufA) + b1) @ W2) * dinv[row]
  fused_agg_gemm<64, 4, 0><<<gfa, TPB, 0, stream>>>(
      (const uint4*)bufA, dinv, csr, offs2, b1, nullptr, PW2, bufB, n);
  // agg1: bufA = relu(L(bufB) + b2) * dinv[row]
  agg_mid_kernel<<<gagg, TPB, 0, stream>>>((const uint4*)bufB, dinv, csr, offs2,
                                           b2, (uint4*)bufA, n);
  // agg2 + gemm3 fused: out = L(bufA) @ W3 + b3  (fp32)
  fused_agg_gemm<40, 3, 1><<<gfa, TPB, 0, stream>>>(
      (const uint4*)bufA, dinv, csr, offs2, nullptr, b3, PW3, d_out, n);
}

// Round 13
// 255.729 us; speedup vs baseline: 1.0770x; 1.0034x over previous
//
#include <hip/hip_runtime.h>
#include <hip/hip_fp16.h>

constexpr int TPB = 256;
constexpr int SH = 8;          // bucket = 256 consecutive destinations
constexpr int BD = 1 << SH;    // 256 dests per bucket (max 512 buckets -> n <= 131072)
constexpr int CHUNK = 4096;    // edges per binning block
constexpr int RMASK = (1 << 23) - 1;  // row in low 23 bits, local dest in high bits
constexpr int MAXCAP = 6144;   // LDS stage bound; cap = 5116 for e=1.6M, nb=391

typedef _Float16 half8 __attribute__((ext_vector_type(8)));
typedef float float4v __attribute__((ext_vector_type(4)));

__device__ __forceinline__ int wave_incl_scan(int x, int lane) {
#pragma unroll
  for (int d = 1; d < 64; d <<= 1) {
    int y = __shfl_up(x, d);
    if (lane >= d) x += y;
  }
  return x;
}

// ---------------- binned CSR build (grouped by destination) ----------------
// Edge entries are packed ints: (local_dest_in_bucket << 23) | src_row.
// v2: LDS counting sort per chunk — entries are staged in bucket order in
// LDS, then written out so consecutive threads hit consecutive global
// addresses within each bucket run (~6x fewer write transactions than the
// old per-edge 4B global scatter).

__global__ __launch_bounds__(256) void bin_kernel(
    const int* __restrict__ row, const int* __restrict__ col,
    int* __restrict__ bcur, int* __restrict__ binned, int e, int nb, int cap) {
  __shared__ int h[512];                 // counts -> cursors
  __shared__ int loc[512];               // chunk-local exclusive offsets
  __shared__ int gb[512];                // base[b] - loc[b]
  __shared__ int wsum4[4];
  __shared__ int stage[CHUNK];
  __shared__ unsigned short sbuck[CHUNK];
  int t = threadIdx.x, lane = t & 63, wv = t >> 6;
  for (int i = t; i < 512; i += 256) h[i] = 0;
  __syncthreads();
  int cb = blockIdx.x * CHUNK;
  int lim = min(cb + CHUNK, e);
  for (int i = cb + t; i < lim; i += 256)
    atomicAdd(&h[col[i] >> SH], 1);
  __syncthreads();
  // scan 512 counts with 256 threads (pairs)
  int v0 = h[2 * t], v1 = h[2 * t + 1];
  int pv = v0 + v1;
  int ps = wave_incl_scan(pv, lane);
  if (lane == 63) wsum4[wv] = ps;
  __syncthreads();
  int woff = 0;
#pragma unroll
  for (int w = 0; w < 4; w++) woff += (w < wv) ? wsum4[w] : 0;
  int ex2 = woff + ps - pv;
  loc[2 * t] = ex2;
  loc[2 * t + 1] = ex2 + v0;
  // claim global segments for this thread's own two buckets; reset cursors
  gb[2 * t]     = v0 ? ((2 * t) * cap + atomicAdd(&bcur[2 * t], v0)) - ex2 : 0;
  gb[2 * t + 1] = v1 ? ((2 * t + 1) * cap + atomicAdd(&bcur[2 * t + 1], v1)) - (ex2 + v0) : 0;
  h[2 * t] = 0;
  h[2 * t + 1] = 0;
  __syncthreads();
  // scatter into LDS in bucket order (int LDS atomics are native)
  for (int i = cb + t; i < lim; i += 256) {
    int c = col[i];
    int b = c >> SH;
    int p = loc[b] + atomicAdd(&h[b], 1);
    stage[p] = ((c & (BD - 1)) << 23) | row[i];
    sbuck[p] = (unsigned short)b;
  }
  __syncthreads();
  // write out: global index = gb[bucket] + s (consecutive within each run)
  int tot = lim - cb;
  for (int s = t; s < tot; s += 256)
    binned[gb[sbuck[s]] + s] = stage[s];
}

// per bucket: fine counts -> scan -> offs2/dinv -> LDS sort -> coalesced csr.
// v2: placement happens in an LDS stage (bucket fits: bcnt <= cap <= MAXCAP),
// csr is then written fully coalesced — no scattered global writes at all.
__global__ __launch_bounds__(512) void count_place_kernel(
    const int* __restrict__ binned, const int* __restrict__ bcnt, int cap,
    int2* __restrict__ offs2, float* __restrict__ dinv, int* __restrict__ csr, int n) {
  __shared__ int cnt[BD];
  __shared__ int wsum[8];
  __shared__ int stage[MAXCAP];
  int t = threadIdx.x, lane = t & 63, wv = t >> 6;
  int b = blockIdx.x;
  int c0 = b << SH;
  int ndst = min(BD, n - c0);
  if (t < BD) cnt[t] = 0;
  __syncthreads();
  int beg = b * cap;
  int end = beg + bcnt[b];
  for (int i = beg + t; i < end; i += 512)
    atomicAdd(&cnt[(unsigned)binned[i] >> 23], 1);
  __syncthreads();
  int v = (t < BD) ? cnt[t] : 0;
  int ps = wave_incl_scan(v, lane);
  if (lane == 63) wsum[wv] = ps;
  __syncthreads();
  int woff = 0;
#pragma unroll
  for (int w = 0; w < 8; w++) woff += (w < wv) ? wsum[w] : 0;
  int ex = woff + ps - v;  // bucket-local exclusive offset
  if (t < ndst) {
    offs2[c0 + t] = make_int2(beg + ex, beg + ex + v);
    dinv[c0 + t] = rsqrtf(1.0f + (float)v);  // deg = incoming + self-loop
  }
  __syncthreads();  // counts consumed; reuse cnt[] as bucket-local cursors
  if (t < BD) cnt[t] = ex;
  __syncthreads();
  for (int i = beg + t; i < end; i += 512) {
    int pv = binned[i];
    int p = atomicAdd(&cnt[(unsigned)pv >> 23], 1);
    stage[p] = pv & RMASK;  // plain row index for the agg kernels
  }
  __syncthreads();
  int tot = end - beg;
  for (int s = t; s < tot; s += 512)
    csr[beg + s] = stage[s];
}

// ---------------- fused weight packing (+ bcur zero) ----------------

// Pack W[K,M] fp32 into B-fragment order for mfma_f32_16x16x32_f16:
// frag f = ct*KT+kt; lane holds B[k=kt*32+(lane>>4)*8+j][n=ct*16+(lane&15)].
template <int K, int M, int CT, int KT>
__device__ __forceinline__ void pack_one(const float* __restrict__ W,
                                         _Float16* __restrict__ P, int idx) {
  if (idx >= CT * KT * 64 * 8) return;
  int j = idx & 7;
  int lane = (idx >> 3) & 63;
  int f = idx >> 9;
  int kt = f % KT, ct = f / KT;
  int c = ct * 16 + (lane & 15);
  int k = kt * 32 + (lane >> 4) * 8 + j;
  float v = (c < M) ? W[k * M + c] : 0.f;
  P[idx] = (_Float16)v;
}

__global__ __launch_bounds__(256) void pack_all_kernel(
    const float* __restrict__ W1, const float* __restrict__ W2,
    const float* __restrict__ W3, _Float16* __restrict__ P1,
    _Float16* __restrict__ P2, _Float16* __restrict__ P3, int* __restrict__ bcur) {
  int blk = blockIdx.x, t = threadIdx.x;
  if (blk < 32) {
    pack_one<128, 64, 4, 4>(W1, P1, blk * 256 + t);
  } else if (blk < 48) {
    pack_one<64, 64, 4, 2>(W2, P2, (blk - 32) * 256 + t);
  } else if (blk < 60) {
    pack_one<64, 40, 3, 2>(W3, P3, (blk - 48) * 256 + t);
  } else {
    bcur[t] = 0;
    bcur[t + 256] = 0;
  }
}

// ---------------- layer-1 MFMA GEMM (fp32 in, fp16 out, dinv pre-scale) -----

template <int K, int M, int CT>
__global__ __launch_bounds__(256) void gemm_mfma_f32in(const float* __restrict__ x,
                                                       const _Float16* __restrict__ PW,
                                                       const float* __restrict__ dinv,
                                                       _Float16* __restrict__ out, int n) {
  constexpr int KT = K / 32;
  int lane = threadIdx.x & 63, wv = threadIdx.x >> 6;
  int m = lane & 15, q = lane >> 4;
  int row0w = blockIdx.x * 64 + wv * 16;
  int arow = row0w + m;
  int ar = arow < n ? arow : n - 1;  // clamp; stores are guarded
  const half8* pw = (const half8*)PW;

  float4v acc[CT];
#pragma unroll
  for (int ct = 0; ct < CT; ct++) acc[ct] = (float4v){0.f, 0.f, 0.f, 0.f};

#pragma unroll
  for (int kt = 0; kt < KT; kt++) {
    const float* xp = x + (size_t)ar * K + kt * 32 + q * 8;
    float4 x0 = *(const float4*)xp;
    float4 x1 = *(const float4*)(xp + 4);
    half8 a;
    a[0] = (_Float16)x0.x; a[1] = (_Float16)x0.y;
    a[2] = (_Float16)x0.z; a[3] = (_Float16)x0.w;
    a[4] = (_Float16)x1.x; a[5] = (_Float16)x1.y;
    a[6] = (_Float16)x1.z; a[7] = (_Float16)x1.w;
#pragma unroll
    for (int ct = 0; ct < CT; ct++) {
      half8 b = pw[(ct * KT + kt) * 64 + lane];
      acc[ct] = __builtin_amdgcn_mfma_f32_16x16x32_f16(a, b, acc[ct], 0, 0, 0);
    }
  }
  // D layout: col = lane&15, row = q*4 + reg
  int r0 = row0w + q * 4;
  float dv[4];
#pragma unroll
  for (int reg = 0; reg < 4; reg++) dv[reg] = (r0 + reg < n) ? dinv[r0 + reg] : 0.f;
#pragma unroll
  for (int ct = 0; ct < CT; ct++) {
    int c = ct * 16 + m;
    if (c < M) {
#pragma unroll
      for (int reg = 0; reg < 4; reg++) {
        int r = r0 + reg;
        if (r < n) out[(size_t)r * M + c] = (_Float16)(acc[ct][reg] * dv[reg]);
      }
    }
  }
}

// ---------------- half-slot aggregation core, BATCH-16 (R10 optimum) --------
// 16-lane slot owns one node. Lanes split into two halves (fl16>>3); half h
// accumulates edges 2j+h of each 16-edge batch, so one dwordx4 gather
// instruction fetches 2 full 128B rows per slot. csr batch for the NEXT
// iteration is prefetched before the current gathers (latency overlap).
// Batch-16 is the measured MLP x occupancy optimum: batch-8 = 2.0 TB/s,
// batch-16 = 2.5 TB/s, batch-32 = 1.84 TB/s (VGPR 88 -> occupancy 16%).
// NOTE: the __shfl broadcast MUST be unconditional — the ej<cnt predicate is
// non-uniform across the two halves; a shfl from an exec-masked-out source
// lane returns undefined data (round-2 bug).
// Caller must xor-8 merge the two halves' partial sums.

__device__ __forceinline__ void h8_add(uint4 u, float* acc) {
  __half2 h0 = *(__half2*)&u.x, h1 = *(__half2*)&u.y;
  __half2 h2 = *(__half2*)&u.z, h3 = *(__half2*)&u.w;
  float2 f0 = __half22float2(h0), f1 = __half22float2(h1);
  float2 f2 = __half22float2(h2), f3 = __half22float2(h3);
  acc[0] += f0.x; acc[1] += f0.y; acc[2] += f1.x; acc[3] += f1.y;
  acc[4] += f2.x; acc[5] += f2.y; acc[6] += f3.x; acc[7] += f3.y;
}

__device__ __forceinline__ uint4 pack_h8(const float* o) {
  __half2 h0 = __float22half2_rn(make_float2(o[0], o[1]));
  __half2 h1 = __float22half2_rn(make_float2(o[2], o[3]));
  __half2 h2 = __float22half2_rn(make_float2(o[4], o[5]));
  __half2 h3 = __float22half2_rn(make_float2(o[6], o[7]));
  uint4 u;
  u.x = *(unsigned*)&h0;
  u.y = *(unsigned*)&h1;
  u.z = *(unsigned*)&h2;
  u.w = *(unsigned*)&h3;
  return u;
}

__device__ __forceinline__ void agg_node(const uint4* __restrict__ xw4,
                                         const int* __restrict__ csr,
                                         int beg, int end, int sb, int half,
                                         int fl, int fl16, float* acc) {
  int b = beg;
  int idx0 = b + fl16;
  int rr = (idx0 < end) ? csr[idx0] : 0;
  while (b < end) {
    int bn = b + 16;
    int idxn = bn + fl16;
    int rn = (idxn < end) ? csr[idxn] : 0;  // prefetch next batch under gathers
    int cnt = end - b;                      // slot-uniform
    uint4 u[8];
    int r[8];
#pragma unroll
    for (int j = 0; j < 8; j++) {
      int ej = 2 * j + half;
      r[j] = __shfl(rr, sb + ej);  // unconditional: all slot lanes active
    }
#pragma unroll
    for (int j = 0; j < 8; j++) {
      int ej = 2 * j + half;
      if (ej < cnt) u[j] = xw4[(size_t)r[j] * 8 + fl];
    }
#pragma unroll
    for (int j = 0; j < 8; j++) {
      int ej = 2 * j + half;
      if (ej < cnt) h8_add(u[j], acc);
    }
    rr = rn;
    b = bn;
  }
}

// ---------------- standalone mid aggregation (layer-2) ----------------
// out = relu(acc*di + b2) * di   (pre-scaled for the layer-3 pre-agg)

__global__ __launch_bounds__(256) void agg_mid_kernel(
    const uint4* __restrict__ xw4, const float* __restrict__ dinv,
    const int* __restrict__ csr, const int2* __restrict__ offs2,
    const float* __restrict__ bias, uint4* __restrict__ out4, int n) {
  int lane = threadIdx.x & 63, wv = threadIdx.x >> 6;
  int sl = lane >> 4, fl16 = lane & 15, half = fl16 >> 3, fl = fl16 & 7;
  int sb = sl << 4;
  int i = blockIdx.x * 16 + wv * 4 + sl;
  bool valid = i < n;
  int ic = valid ? i : n - 1;
  int2 oe = offs2[ic];
  int beg = oe.x;
  int end = valid ? oe.y : beg;
  float di = dinv[ic];
  float acc[8] = {0.f, 0.f, 0.f, 0.f, 0.f, 0.f, 0.f, 0.f};
  if (!half) h8_add(xw4[(size_t)ic * 8 + fl], acc);  // self-loop (pre-scaled row)
  agg_node(xw4, csr, beg, end, sb, half, fl, fl16, acc);
#pragma unroll
  for (int k = 0; k < 8; k++) acc[k] += __shfl_xor(acc[k], 8);

  if (valid && !half) {
    const float4* b4 = (const float4*)bias;
    float4 ba = b4[fl * 2], bb = b4[fl * 2 + 1];
    float o[8];
    o[0] = fmaxf(acc[0] * di + ba.x, 0.f) * di;
    o[1] = fmaxf(acc[1] * di + ba.y, 0.f) * di;
    o[2] = fmaxf(acc[2] * di + ba.z, 0.f) * di;
    o[3] = fmaxf(acc[3] * di + ba.w, 0.f) * di;
    o[4] = fmaxf(acc[4] * di + bb.x, 0.f) * di;
    o[5] = fmaxf(acc[5] * di + bb.y, 0.f) * di;
    o[6] = fmaxf(acc[6] * di + bb.z, 0.f) * di;
    o[7] = fmaxf(acc[7] * di + bb.w, 0.f) * di;
    out4[(size_t)i * 8 + fl] = pack_h8(o);
  }
}

// ---------------- fused aggregation + MFMA GEMM (R10: 64 dests/block) -------
// Block owns 64 destination rows: 16 slots x 4 sequential nodes aggregate into
// an LDS fp16 tile (stride 72 halves = 144B), then 4 waves run the K=64 MFMA
// GEMM straight from LDS. NOTE: no cross-node prefetch arrays — runtime-
// indexed register arrays in the un-unrolled node loop go to scratch
// (round-9 regression, −20 µs/kernel).
// FMODE 0 (layers 1->2): agg epilogue relu(acc*di + biasA); gemm out fp16 *dinv[r].
// FMODE 1 (layer 3):     agg epilogue acc*di;               gemm out fp32 + biasG.

template <int M, int CT, int FMODE>
__global__ __launch_bounds__(256) void fused_agg_gemm(
    const uint4* __restrict__ xw4, const float* __restrict__ dinv,
    const int* __restrict__ csr, const int2* __restrict__ offs2,
    const float* __restrict__ biasA, const float* __restrict__ biasG,
    const _Float16* __restrict__ PW, void* __restrict__ outp, int n) {
  constexpr int KT = 2;  // K = 64
  __shared__ _Float16 tile[64 * 72];
  int lane = threadIdx.x & 63, wv = threadIdx.x >> 6;
  int sl = lane >> 4, fl16 = lane & 15, half = fl16 >> 3, fl = fl16 & 7;
  int sb = sl << 4;
  int slot_id = wv * 4 + sl;  // 0..15
  int base = blockIdx.x * 64;

#pragma unroll 1
  for (int nd = 0; nd < 4; nd++) {
    int l = slot_id * 4 + nd;  // local row 0..63
    int i = base + l;
    bool valid = i < n;
    int ic = valid ? i : n - 1;
    int2 oe = offs2[ic];
    int beg = oe.x;
    int end = valid ? oe.y : beg;
    float di = dinv[ic];
    float acc[8] = {0.f, 0.f, 0.f, 0.f, 0.f, 0.f, 0.f, 0.f};
    if (!half) h8_add(xw4[(size_t)ic * 8 + fl], acc);  // self-loop
    agg_node(xw4, csr, beg, end, sb, half, fl, fl16, acc);
#pragma unroll
    for (int k = 0; k < 8; k++) acc[k] += __shfl_xor(acc[k], 8);

    float o[8];
    if (FMODE == 0) {
      const float4* b4 = (const float4*)biasA;
      float4 ba = b4[fl * 2], bb = b4[fl * 2 + 1];
      o[0] = fmaxf(acc[0] * di + ba.x, 0.f);
      o[1] = fmaxf(acc[1] * di + ba.y, 0.f);
      o[2] = fmaxf(acc[2] * di + ba.z, 0.f);
      o[3] = fmaxf(acc[3] * di + ba.w, 0.f);
      o[4] = fmaxf(acc[4] * di + bb.x, 0.f);
      o[5] = fmaxf(acc[5] * di + bb.y, 0.f);
      o[6] = fmaxf(acc[6] * di + bb.z, 0.f);
      o[7] = fmaxf(acc[7] * di + bb.w, 0.f);
    } else {
#pragma unroll
      for (int k = 0; k < 8; k++) o[k] = acc[k] * di;
    }
    if (!half) *(uint4*)&tile[(size_t)l * 72 + fl * 8] = pack_h8(o);
  }
  __syncthreads();

  // ---- MFMA phase (same fragment mapping as the standalone GEMMs) ----
  int m = lane & 15, q = lane >> 4;
  int lrow = wv * 16 + m;
  const half8* pw = (const half8*)PW;
  float4v accd[CT];
#pragma unroll
  for (int ct = 0; ct < CT; ct++) accd[ct] = (float4v){0.f, 0.f, 0.f, 0.f};
#pragma unroll
  for (int kt = 0; kt < KT; kt++) {
    half8 a = *(const half8*)&tile[lrow * 72 + kt * 32 + q * 8];
#pragma unroll
    for (int ct = 0; ct < CT; ct++) {
      half8 b = pw[(ct * KT + kt) * 64 + lane];
      accd[ct] = __builtin_amdgcn_mfma_f32_16x16x32_f16(a, b, accd[ct], 0, 0, 0);
    }
  }
  int r0 = base + wv * 16 + q * 4;
  if (FMODE == 0) {
    _Float16* out = (_Float16*)outp;
    float dv[4];
#pragma unroll
    for (int reg = 0; reg < 4; reg++) dv[reg] = (r0 + reg < n) ? dinv[r0 + reg] : 0.f;
#pragma unroll
    for (int ct = 0; ct < CT; ct++) {
      int c = ct * 16 + m;
      if (c < M) {
#pragma unroll
        for (int reg = 0; reg < 4; reg++) {
          int r = r0 + reg;
          if (r < n) out[(size_t)r * M + c] = (_Float16)(accd[ct][reg] * dv[reg]);
        }
      }
    }
  } else {
    float* out = (float*)outp;
#pragma unroll
    for (int ct = 0; ct < CT; ct++) {
      int c = ct * 16 + m;
      if (c < M) {
        float bb = biasG[c];
#pragma unroll
        for (int reg = 0; reg < 4; reg++) {
          int r = r0 + reg;
          if (r < n) out[(size_t)r * M + c] = accd[ct][reg] + bb;
        }
      }
    }
  }
}

// ---------------- launcher ----------------

extern "C" void kernel_launch(void* const* d_in, const int* in_sizes, int n_in,
                              void* d_out, int out_size, void* d_ws, size_t ws_size,
                              hipStream_t stream) {
  const float* x  = (const float*)d_in[0];
  const int*   ei = (const int*)d_in[1];
  const float* W1 = (const float*)d_in[2];
  const float* b1 = (const float*)d_in[3];
  const float* W2 = (const float*)d_in[4];
  const float* b2 = (const float*)d_in[5];
  const float* W3 = (const float*)d_in[6];
  const float* b3 = (const float*)d_in[7];

  int n = in_sizes[0] / 128;
  int e = in_sizes[1] / 2;
  const int* rowA = ei;      // edge_index[0] = source
  const int* colA = ei + e;  // edge_index[1] = destination (segment id)

  int nb = (n + BD - 1) >> SH;  // buckets (<= 512)
  int meanb = e / nb;
  int cap = meanb + (meanb / 4 > 1024 ? meanb / 4 : 1024);  // generous slack
  if (cap > MAXCAP) cap = MAXCAP;  // LDS stage bound (5116 for this shape)
  int nch = (e + CHUNK - 1) / CHUNK;

  size_t off = 0;
  auto alloc = [&](size_t bytes) {
    void* p = (char*)d_ws + off;
    off += (bytes + 255) & ~(size_t)255;
    return p;
  };
  // bufA (n*64*4 B) also aliases the binned edge array (nb*cap*4 << n*256 B)
  __half* bufA  = (__half*)alloc((size_t)n * 64 * 4);
  __half* bufB  = (__half*)alloc((size_t)n * 64 * 4);
  int2*  offs2  = (int2*)alloc((size_t)n * 8);
  float* dinv   = (float*)alloc((size_t)n * 4);
  int*   csr    = (int*)alloc((size_t)nb * cap * 4);
  int*   bcur   = (int*)alloc(512 * 4);
  _Float16* PW1 = (_Float16*)alloc(4 * 4 * 64 * 8 * 2);  // CT=4, KT=4
  _Float16* PW2 = (_Float16*)alloc(4 * 2 * 64 * 8 * 2);  // CT=4, KT=2
  _Float16* PW3 = (_Float16*)alloc(3 * 2 * 64 * 8 * 2);  // CT=3, KT=2
  int*   binned = (int*)bufA;  // consumed by count_place before gemm1 writes bufA
  (void)ws_size; (void)n_in; (void)out_size;

  // fused: pack all three W matrices + zero bcur (one dispatch)
  pack_all_kernel<<<61, TPB, 0, stream>>>(W1, W2, W3, PW1, PW2, PW3, bcur);
  bin_kernel<<<nch, TPB, 0, stream>>>(rowA, colA, bcur, binned, e, nb, cap);
  count_place_kernel<<<nb, 512, 0, stream>>>(binned, bcur, cap, offs2, dinv, csr, n);

  int gmf = (n + 63) / 64;   // 64 rows/block
  int gagg = (n + 15) / 16;  // 16 nodes/block (4 slots/wave x 4 waves)

  // L1 GEMM: bufA = (x @ W1) * dinv[row]
  gemm_mfma_f32in<128, 64, 4><<<gmf, TPB, 0, stream>>>(x, PW1, dinv, (_Float16*)bufA, n);
  // agg0 + gemm2 fused: bufB = (relu(L(bufA) + b1) @ W2) * dinv[row]
  fused_agg_gemm<64, 4, 0><<<gmf, TPB, 0, stream>>>(
      (const uint4*)bufA, dinv, csr, offs2, b1, nullptr, PW2, bufB, n);
  // agg1: bufA = relu(L(bufB) + b2) * dinv[row]
  agg_mid_kernel<<<gagg, TPB, 0, stream>>>((const uint4*)bufB, dinv, csr, offs2,
                                           b2, (uint4*)bufA, n);
  // agg2 + gemm3 fused: out = L(bufA) @ W3 + b3  (fp32)
  fused_agg_gemm<40, 3, 1><<<gmf, TPB, 0, stream>>>(
      (const uint4*)bufA, dinv, csr, offs2, nullptr, b3, PW3, d_out, n);
}